// Round 7
// baseline (21.278 us; speedup 1.0000x reference)
//
#include <hip/hip_runtime.h>
#include <math.h>

#define SR_I 16000
#define FRAMES 500
#define UP 64
#define AUDIO (FRAMES * UP)
#define POLY 8
#define HARM 64
#define NYQ 8000.0f
#define NOSC (POLY * HARM)   // 512

// -------------------------------------------------------------------------
// Kernel A: transpose c[b,p,k,t] -> cT[b,t,p*64+k] so the main kernel's
// per-frame harmonic reads are coalesced (256 B contiguous per wave) instead
// of 64-distinct-line gathers.  Classic LDS 64x64 tile, +1 pad (2-way bank
// aliasing only, which is free).
// -------------------------------------------------------------------------
__global__ __launch_bounds__(256) void k_transpose(const float* __restrict__ cc,
                                                   float* __restrict__ cT) {
    __shared__ float tile[64][65];
    const int blk = blockIdx.x;            // (b*8+p)*8 + chunk
    const int chunk = blk & 7;
    const int bp = blk >> 3;               // b*8+p
    const int tc = chunk * 64;
    const int w = threadIdx.x >> 6;        // wave 0..3
    const int l = threadIdx.x & 63;

    const float* src = cc + (size_t)bp * HARM * FRAMES;

    #pragma unroll
    for (int i = 0; i < 16; ++i) {         // load: coalesced along t
        const int r = w * 16 + i;          // harmonic row
        const int t = tc + l;
        tile[r][l] = (t < FRAMES) ? src[r * FRAMES + t] : 0.0f;
    }
    __syncthreads();
    const int b = bp >> 3, p = bp & 7;
    #pragma unroll
    for (int i = 0; i < 16; ++i) {         // store: coalesced along k
        const int tl = w * 16 + i;
        const int t = tc + tl;
        if (t < FRAMES)
            cT[(size_t)(b * FRAMES + t) * NOSC + p * HARM + l] = tile[l][tl];
    }
}

// -------------------------------------------------------------------------
// Kernel B (main): one block per (b, frame t); 8 waves; wave p = voice p.
// Lane k owns output sample j = t*64 + k.  Identical math to the passing R6
// kernel; only the c reads changed (coalesced from cT).
//
// Frame prefix (closed form): P[t] = (64*S_t + 8*(x[t]-x[t-1]))/SR,
//   S_t = sum_{j<t} x[j].
// In-frame inclusive scan (closed form, increments linear in lane k):
//   lanes 0..31 : S(k) = [(k+1)A + (B-A)(k(k+1)/2 + 32.5(k+1))/64]/SR
//   lanes 32..63: q=k-32, S = (8A+24B)/SR + [(q+1)B + (C-B)(q+1)^2/128]/SR
// Anti-alias mask baked into LDS quads at staging; harmonic loop is
// ds_read_b128 + 3 fma + fract + v_sin + fma, 4x unrolled.
// -------------------------------------------------------------------------
__global__ __launch_bounds__(512) void k_fused(const float* __restrict__ f0,
                                               const float* __restrict__ cT,
                                               const float* __restrict__ vv,
                                               const float* __restrict__ rp,
                                               float* __restrict__ out) {
    __shared__ float4 quads[POLY][2][HARM];   // 16 KiB
    __shared__ float part[POLY][UP];          // 2 KiB

    const int blk = blockIdx.x;           // 0 .. 2*FRAMES-1
    const int b = blk / FRAMES;
    const int t = blk - b * FRAMES;
    const int tid = threadIdx.x;
    const int p = tid >> 6;               // wave index = voice
    const int k = tid & 63;
    const bool lowhalf = (k < 32);

    const int tm = max(t - 1, 0);
    const int tp = min(t + 1, FRAMES - 1);

    const int bpi = b * POLY + p;
    const float* f0p = f0 + bpi * FRAMES;
    const float* vp  = vv + bpi * FRAMES;

    // ---- issue ALL global loads up-front, mutually independent ----
    // coalesced c reads from the transposed layout (4 cache lines each)
    const float* cTb = cT + (size_t)b * FRAMES * NOSC + p * HARM + k;
    const float craw_m = cTb[(size_t)tm * NOSC];
    const float craw_c = cTb[(size_t)t  * NOSC];
    const float craw_p = cTb[(size_t)tp * NOSC];
    const float rpl    = rp[bpi * HARM + k];

    float pre[8];                                  // predicated prefix loads
    #pragma unroll
    for (int u = 0; u < 8; ++u) {
        const int j = k + u * 64;
        pre[u] = (j < t) ? f0p[j] : 0.0f;
    }

    const float A = f0p[tm];
    const float B = f0p[t];
    const float C = f0p[tp];
    const float vA = vp[tm];
    const float vB = vp[t];
    const float vC = vp[tp];

    // ---- stage pre-masked quads: lane k holds harmonic k (n = k+1) ----
    const float nf = (float)(k + 1);
    const bool mA = (nf * A < NYQ);
    const bool mB = (nf * B < NYQ);
    const bool mC = (nf * C < NYQ);
    const float cA = mA ? craw_m : 0.0f;
    const float cB = mB ? craw_c : 0.0f;
    const float cC = mC ? craw_p : 0.0f;
    quads[p][0][k] = make_float4(cA, cB, rpl, 0.0f);   // lanes 0..31: (i0,i1)=(tm,t)
    quads[p][1][k] = make_float4(cB, cC, rpl, 0.0f);   // lanes 32..63: (t,tp)

    // wave-uniform harmonic cap (mask monotone in n)
    const unsigned long long bal = __ballot(mA || mB || mC);
    int hmax = (int)__popcll(bal);
    hmax = (hmax + 3) & ~3;

    // ---- frame prefix P[t] (f64) from the predicated loads ----
    double ssum = 0.0;
    #pragma unroll
    for (int u = 0; u < 8; ++u) ssum += (double)pre[u];
    #pragma unroll
    for (int off = 32; off; off >>= 1)
        ssum += __shfl_xor(ssum, off, 64);
    const double dA = (double)A, dB = (double)B, dC = (double)C;
    const double Pfr = (64.0 * ssum + 8.0 * (dB - dA)) * (1.0 / (double)SR_I);

    // ---- in-frame inclusive scan, closed form ----
    double S;
    if (lowhalf) {
        const double kk = (double)k;
        S = ((kk + 1.0) * dA
             + (dB - dA) * (kk * (kk + 1.0) * 0.5 + 32.5 * (kk + 1.0)) * (1.0 / 64.0))
            * (1.0 / (double)SR_I);
    } else {
        const double qq = (double)(k - 32);
        S = (8.0 * dA + 24.0 * dB) * (1.0 / (double)SR_I)
            + ((qq + 1.0) * dB + (dC - dB) * (qq + 1.0) * (qq + 1.0) * (1.0 / 128.0))
              * (1.0 / (double)SR_I);
    }
    const double Phi = Pfr + S;
    const float phi = (float)(Phi - floor(Phi));   // exact frac, then f32

    // per-lane interpolation weights and v envelope
    const float w = (lowhalf ? ((float)k + 32.5f) : ((float)k - 31.5f)) * (1.0f / 64.0f);
    const float w1 = 1.0f - w;
    const float v0 = lowhalf ? vA : vB;
    const float v1 = lowhalf ? vB : vC;
    const float vup04 = 0.04f * (w1 * v0 + w * v1);
    const float W0 = w1 * vup04;
    const float W1 = w * vup04;

    const float4* qb = &quads[p][lowhalf ? 0 : 1][0];

    float acc0 = 0.0f, acc1 = 0.0f, acc2 = 0.0f, acc3 = 0.0f;
    float nf0 = 1.0f, nf1 = 2.0f, nf2 = 3.0f, nf3 = 4.0f;

    for (int n0 = 1; n0 <= hmax; n0 += 4) {
        const float4 qa = qb[n0 - 1];
        const float4 qc = qb[n0 + 0];
        const float4 qd = qb[n0 + 1];
        const float4 qe = qb[n0 + 2];

        {
            const float cup = fmaf(W1, qa.y, W0 * qa.x);
            const float ph  = fmaf(nf0, phi, qa.z);
            acc0 = fmaf(cup, __builtin_amdgcn_sinf(__builtin_amdgcn_fractf(ph)), acc0);
        }
        {
            const float cup = fmaf(W1, qc.y, W0 * qc.x);
            const float ph  = fmaf(nf1, phi, qc.z);
            acc1 = fmaf(cup, __builtin_amdgcn_sinf(__builtin_amdgcn_fractf(ph)), acc1);
        }
        {
            const float cup = fmaf(W1, qd.y, W0 * qd.x);
            const float ph  = fmaf(nf2, phi, qd.z);
            acc2 = fmaf(cup, __builtin_amdgcn_sinf(__builtin_amdgcn_fractf(ph)), acc2);
        }
        {
            const float cup = fmaf(W1, qe.y, W0 * qe.x);
            const float ph  = fmaf(nf3, phi, qe.z);
            acc3 = fmaf(cup, __builtin_amdgcn_sinf(__builtin_amdgcn_fractf(ph)), acc3);
        }
        nf0 += 4.0f; nf1 += 4.0f; nf2 += 4.0f; nf3 += 4.0f;
    }

    part[p][k] = (acc0 + acc1) + (acc2 + acc3);
    __syncthreads();
    if (tid < 64) {
        float sum = 0.0f;
        #pragma unroll
        for (int q = 0; q < POLY; ++q) sum += part[q][tid];
        out[(size_t)b * AUDIO + t * UP + tid] = sum;
    }
}

extern "C" void kernel_launch(void* const* d_in, const int* in_sizes, int n_in,
                              void* d_out, int out_size, void* d_ws, size_t ws_size,
                              hipStream_t stream) {
    const float* f0 = (const float*)d_in[0];   // (2,8,500)
    const float* c  = (const float*)d_in[1];   // (2,8,64,500)
    const float* v  = (const float*)d_in[2];   // (2,8,500)
    // d_in[3] = a (loudness) — unused by the output
    const float* rp = (const float*)d_in[4];   // (2,512,1)
    float* out = (float*)d_out;                // (2,32000)

    float* cT = (float*)d_ws;                  // 2*500*512*4 B = 2 MB

    k_transpose<<<2 * POLY * 8, 256, 0, stream>>>(c, cT);
    k_fused<<<2 * FRAMES, 512, 0, stream>>>(f0, cT, v, rp, out);
}

// Round 8
// 17.738 us; speedup vs baseline: 1.1996x; 1.1996x over previous
//
#include <hip/hip_runtime.h>
#include <math.h>

#define SR_I 16000
#define FRAMES 500
#define UP 64
#define AUDIO (FRAMES * UP)
#define POLY 8
#define HARM 64
#define NYQ 8000.0f

// -------------------------------------------------------------------------
// Single fused kernel: one block per (b, frame t); 8 waves.
// PROLOGUE: wave p stages voice p (pre-masked quads, phase via closed forms,
//   per-lane weights) into LDS.
// MAIN LOOP (after one barrier): waves are decoupled from voices — wave w
//   processes quad-slots {(w+p)&7, ((w+p)&7)+8} of EVERY voice p (Latin-
//   square rotation: all 16 slots of all voices covered exactly once, each
//   wave gets a uniform mix of cheap/expensive slots).  The grid is fully
//   co-resident (8000/8192 wave slots), so makespan = slowest wave; this
//   balances it (worst wave ~6-8 quads instead of 16).
//
// Phase math (all exact f64, unchanged from the passing R5/R6 kernels):
//   P[t] = (64*S_t + 8*(x[t]-x[t-1]))/SR,  S_t = sum_{j<t} x[j]
//   lanes 0..31 : S(k) = [(k+1)A + (B-A)(k(k+1)/2 + 32.5(k+1))/64]/SR
//   lanes 32..63: q=k-32, S = (8A+24B)/SR + [(q+1)B + (C-B)(q+1)^2/128]/SR
// Anti-alias mask baked into quads at staging; per-quad inner body is
// 4 x { ds_read_b128(bcast) + 3 fma + fract + v_sin + fma }.
// -------------------------------------------------------------------------
__global__ __launch_bounds__(512) void k_fused(const float* __restrict__ f0,
                                               const float* __restrict__ cc,
                                               const float* __restrict__ vv,
                                               const float* __restrict__ rp,
                                               float* __restrict__ out) {
    __shared__ float4 quads[POLY][2][HARM];   // 16 KiB
    __shared__ float4 phiW[POLY][UP];         //  8 KiB: (phi, W0, W1, -)
    __shared__ float part[POLY][UP];          //  2 KiB
    __shared__ int hmaxs[POLY];

    const int blk = blockIdx.x;           // 0 .. 2*FRAMES-1
    const int b = blk / FRAMES;
    const int t = blk - b * FRAMES;
    const int tid = threadIdx.x;
    const int wv = tid >> 6;              // wave index (= staged voice)
    const int k = tid & 63;
    const bool lowhalf = (k < 32);

    const int tm = max(t - 1, 0);
    const int tp = min(t + 1, FRAMES - 1);

    const int bpi = b * POLY + wv;
    const float* f0p = f0 + bpi * FRAMES;
    const float* vp  = vv + bpi * FRAMES;
    const float* cp  = cc + (size_t)bpi * HARM * FRAMES;

    // ---- issue all global loads up-front, mutually independent ----
    const float craw_m = cp[k * FRAMES + tm];
    const float craw_c = cp[k * FRAMES + t];
    const float craw_p = cp[k * FRAMES + tp];
    const float rpl    = rp[bpi * HARM + k];

    float pre[8];
    #pragma unroll
    for (int u = 0; u < 8; ++u) {
        const int j = k + u * 64;
        pre[u] = (j < t) ? f0p[j] : 0.0f;
    }

    const float A = f0p[tm];
    const float B = f0p[t];
    const float C = f0p[tp];
    const float vA = vp[tm];
    const float vB = vp[t];
    const float vC = vp[tp];

    // ---- stage pre-masked quads: lane k = harmonic k+1 of voice wv ----
    const float nf = (float)(k + 1);
    const bool mA = (nf * A < NYQ);
    const bool mB = (nf * B < NYQ);
    const bool mC = (nf * C < NYQ);
    quads[wv][0][k] = make_float4(mA ? craw_m : 0.0f, mB ? craw_c : 0.0f, rpl, 0.0f);
    quads[wv][1][k] = make_float4(mB ? craw_c : 0.0f, mC ? craw_p : 0.0f, rpl, 0.0f);

    const unsigned long long bal = __ballot(mA || mB || mC);
    int hmax = (int)__popcll(bal);        // mask monotone in n
    hmax = (hmax + 3) & ~3;
    if (k == 0) hmaxs[wv] = hmax;

    // ---- frame prefix P[t] (f64) ----
    double ssum = 0.0;
    #pragma unroll
    for (int u = 0; u < 8; ++u) ssum += (double)pre[u];
    #pragma unroll
    for (int off = 32; off; off >>= 1)
        ssum += __shfl_xor(ssum, off, 64);
    const double dA = (double)A, dB = (double)B, dC = (double)C;
    const double Pfr = (64.0 * ssum + 8.0 * (dB - dA)) * (1.0 / (double)SR_I);

    // ---- in-frame inclusive scan, closed form ----
    double S;
    if (lowhalf) {
        const double kk = (double)k;
        S = ((kk + 1.0) * dA
             + (dB - dA) * (kk * (kk + 1.0) * 0.5 + 32.5 * (kk + 1.0)) * (1.0 / 64.0))
            * (1.0 / (double)SR_I);
    } else {
        const double qq = (double)(k - 32);
        S = (8.0 * dA + 24.0 * dB) * (1.0 / (double)SR_I)
            + ((qq + 1.0) * dB + (dC - dB) * (qq + 1.0) * (qq + 1.0) * (1.0 / 128.0))
              * (1.0 / (double)SR_I);
    }
    const double Phi = Pfr + S;
    const float phi = (float)(Phi - floor(Phi));

    // per-lane weights / envelope -> publish to LDS
    const float w = (lowhalf ? ((float)k + 32.5f) : ((float)k - 31.5f)) * (1.0f / 64.0f);
    const float w1 = 1.0f - w;
    const float v0 = lowhalf ? vA : vB;
    const float v1 = lowhalf ? vB : vC;
    const float vup04 = 0.04f * (w1 * v0 + w * v1);
    phiW[wv][k] = make_float4(phi, w1 * vup04, w * vup04, 0.0f);

    __syncthreads();

    // ---- balanced harmonic loop: wave wv takes slots {(wv+p)&7, +8} of p --
    const int half = lowhalf ? 0 : 1;
    float acc0 = 0.0f, acc1 = 0.0f, acc2 = 0.0f, acc3 = 0.0f;

    auto do_quad = [&](const float4* q4, float base, const float4& pw) {
        const float4 qa = q4[0], qc = q4[1], qd = q4[2], qe = q4[3];
        {
            const float cup = fmaf(pw.z, qa.y, pw.y * qa.x);
            const float ph  = fmaf(base + 1.0f, pw.x, qa.z);
            acc0 = fmaf(cup, __builtin_amdgcn_sinf(__builtin_amdgcn_fractf(ph)), acc0);
        }
        {
            const float cup = fmaf(pw.z, qc.y, pw.y * qc.x);
            const float ph  = fmaf(base + 2.0f, pw.x, qc.z);
            acc1 = fmaf(cup, __builtin_amdgcn_sinf(__builtin_amdgcn_fractf(ph)), acc1);
        }
        {
            const float cup = fmaf(pw.z, qd.y, pw.y * qd.x);
            const float ph  = fmaf(base + 3.0f, pw.x, qd.z);
            acc2 = fmaf(cup, __builtin_amdgcn_sinf(__builtin_amdgcn_fractf(ph)), acc2);
        }
        {
            const float cup = fmaf(pw.z, qe.y, pw.y * qe.x);
            const float ph  = fmaf(base + 4.0f, pw.x, qe.z);
            acc3 = fmaf(cup, __builtin_amdgcn_sinf(__builtin_amdgcn_fractf(ph)), acc3);
        }
    };

    #pragma unroll
    for (int pv = 0; pv < POLY; ++pv) {
        const int sA = (wv + pv) & 7;         // rotated slot 0..7
        const int hm = hmaxs[pv];             // wave-uniform -> scalar branch
        if (sA * 4 < hm) {
            const float4 pw = phiW[pv][k];
            const float4* qb = &quads[pv][half][0];
            do_quad(qb + 4 * sA, (float)(4 * sA), pw);
            const int sB = sA + 8;            // slot 8..15 (harmonics 33..64)
            if (sB * 4 < hm)
                do_quad(qb + 4 * sB, (float)(4 * sB), pw);
        }
    }

    part[wv][k] = (acc0 + acc1) + (acc2 + acc3);
    __syncthreads();
    if (tid < 64) {
        float sum = 0.0f;
        #pragma unroll
        for (int q = 0; q < POLY; ++q) sum += part[q][tid];
        out[(size_t)b * AUDIO + t * UP + tid] = sum;
    }
}

extern "C" void kernel_launch(void* const* d_in, const int* in_sizes, int n_in,
                              void* d_out, int out_size, void* d_ws, size_t ws_size,
                              hipStream_t stream) {
    const float* f0 = (const float*)d_in[0];   // (2,8,500)
    const float* c  = (const float*)d_in[1];   // (2,8,64,500)
    const float* v  = (const float*)d_in[2];   // (2,8,500)
    // d_in[3] = a (loudness) — unused by the output
    const float* rp = (const float*)d_in[4];   // (2,512,1)
    float* out = (float*)d_out;                // (2,32000)

    k_fused<<<2 * FRAMES, 512, 0, stream>>>(f0, c, v, rp, out);
}

// Round 9
// 16.862 us; speedup vs baseline: 1.2619x; 1.0519x over previous
//
#include <hip/hip_runtime.h>
#include <math.h>

#define SR_I 16000
#define FRAMES 500
#define UP 64
#define AUDIO (FRAMES * UP)
#define POLY 8
#define HARM 64
#define NYQ 8000.0f

// -------------------------------------------------------------------------
// Single fused kernel, TWO frames per block: block g handles frames
// t0=2g, t1=2g+1 of batch b; 8 waves; wave p = voice p; lane k owns output
// sample (t,k).  Frames t0,t1 share inputs: c[k,t0-1..t0+2] (4 gathers),
// f0/v at 4 indices, one rp load, and ONE prefix reduction
// (S_{t1} = S_{t0} + x[t0]).  This halves per-output prologue latency —
// the measured bottleneck (VALUBusy ~24%, HBM ~2%, whole grid co-resident).
//
// Phase math (exact f64, identical to the passing R5 kernel per frame):
//   P[t] = (64*S_t + 8*(x[t]-x[t-1]))/SR,  S_t = sum_{j<t} x[j]
//   in-frame inclusive scan, closed form (increments linear in lane k):
//     lanes 0..31 : S(k) = [(k+1)A + (B-A)(k(k+1)/2 + 32.5(k+1))/64]/SR
//     lanes 32..63: q=k-32, S = (8A+24B)/SR + [(q+1)B + (C-B)(q+1)^2/128]/SR
//   (A,B,C) = f0 at (t-1,t,t+1), clamped at array ends.
// Anti-alias mask baked into LDS quads at staging; harmonic loop is
// ds_read_b128(bcast) + 3 fma + fract + v_sin + fma, 4x unrolled.
// Quads are wave-local (written and read by the same wave) -> no barrier
// until the final cross-wave reduce.
// -------------------------------------------------------------------------
__global__ __launch_bounds__(512) void k_fused(const float* __restrict__ f0,
                                               const float* __restrict__ cc,
                                               const float* __restrict__ vv,
                                               const float* __restrict__ rp,
                                               float* __restrict__ out) {
    __shared__ float4 quads[2][POLY][2][HARM];   // 32 KiB: [frame][voice][half][lane]
    __shared__ float part[2][POLY][UP];          //  4 KiB

    const int blk = blockIdx.x;            // 0 .. 2*(FRAMES/2)-1
    const int b = blk / (FRAMES / 2);
    const int g = blk - b * (FRAMES / 2);
    const int t0 = 2 * g;
    const int t1 = t0 + 1;
    const int tid = threadIdx.x;
    const int p = tid >> 6;                // wave index = voice
    const int k = tid & 63;
    const bool lowhalf = (k < 32);

    const int tm = max(t0 - 1, 0);         // frame t0-1 (clamped)
    const int tq = min(t0 + 2, FRAMES - 1); // frame t0+2 (clamped)

    const int bpi = b * POLY + p;
    const float* f0p = f0 + bpi * FRAMES;
    const float* vp  = vv + bpi * FRAMES;
    const float* cp  = cc + (size_t)bpi * HARM * FRAMES;

    // ---- issue ALL global loads up-front, mutually independent ----
    const float cm = cp[k * FRAMES + tm];    // c[k] at t0-1, t0, t1, t0+2
    const float cb = cp[k * FRAMES + t0];
    const float cx = cp[k * FRAMES + t1];
    const float cd = cp[k * FRAMES + tq];
    const float rpl = rp[bpi * HARM + k];

    float pre[8];                             // predicated prefix loads (j < t0)
    #pragma unroll
    for (int u = 0; u < 8; ++u) {
        const int j = k + u * 64;
        pre[u] = (j < t0) ? f0p[j] : 0.0f;
    }

    const float A = f0p[tm];
    const float B = f0p[t0];
    const float C = f0p[t1];
    const float D = f0p[tq];
    const float vA = vp[tm];
    const float vB = vp[t0];
    const float vC = vp[t1];
    const float vD = vp[tq];

    // ---- masks (per source frame) and pre-masked quads for both frames ----
    const float nf = (float)(k + 1);
    const bool mA = (nf * A < NYQ);
    const bool mB = (nf * B < NYQ);
    const bool mC = (nf * C < NYQ);
    const bool mD = (nf * D < NYQ);
    const float qA = mA ? cm : 0.0f;
    const float qB = mB ? cb : 0.0f;
    const float qC = mC ? cx : 0.0f;
    const float qD = mD ? cd : 0.0f;
    // frame0 interp sources: low (t0-1, t0), high (t0, t1)
    quads[0][p][0][k] = make_float4(qA, qB, rpl, 0.0f);
    quads[0][p][1][k] = make_float4(qB, qC, rpl, 0.0f);
    // frame1 interp sources: low (t0, t1), high (t1, t0+2)
    quads[1][p][0][k] = make_float4(qB, qC, rpl, 0.0f);
    quads[1][p][1][k] = make_float4(qC, qD, rpl, 0.0f);

    // wave-uniform harmonic caps (mask monotone in n)
    int hm0 = (int)__popcll(__ballot(mA || mB || mC));
    int hm1 = (int)__popcll(__ballot(mB || mC || mD));
    hm0 = (hm0 + 3) & ~3;
    hm1 = (hm1 + 3) & ~3;

    // ---- frame prefix sums (f64): one reduction serves both frames ----
    double ssum = 0.0;
    #pragma unroll
    for (int u = 0; u < 8; ++u) ssum += (double)pre[u];
    #pragma unroll
    for (int off = 32; off; off >>= 1)
        ssum += __shfl_xor(ssum, off, 64);
    const double dA = (double)A, dB = (double)B, dC = (double)C, dD = (double)D;
    const double Pfr0 = (64.0 * ssum + 8.0 * (dB - dA)) * (1.0 / (double)SR_I);
    const double Pfr1 = (64.0 * (ssum + dB) + 8.0 * (dC - dB)) * (1.0 / (double)SR_I);

    // ---- in-frame inclusive scans, closed form ----
    const double kk = (double)k;
    const double qq = (double)(k - 32);
    double S0, S1;
    if (lowhalf) {
        const double lin = (kk * (kk + 1.0) * 0.5 + 32.5 * (kk + 1.0)) * (1.0 / 64.0);
        S0 = ((kk + 1.0) * dA + (dB - dA) * lin) * (1.0 / (double)SR_I);
        S1 = ((kk + 1.0) * dB + (dC - dB) * lin) * (1.0 / (double)SR_I);
    } else {
        const double sq = (qq + 1.0) * (qq + 1.0) * (1.0 / 128.0);
        S0 = (8.0 * dA + 24.0 * dB + (qq + 1.0) * dB + (dC - dB) * sq) * (1.0 / (double)SR_I);
        S1 = (8.0 * dB + 24.0 * dC + (qq + 1.0) * dC + (dD - dC) * sq) * (1.0 / (double)SR_I);
    }
    const double Phi0 = Pfr0 + S0;
    const double Phi1 = Pfr1 + S1;
    const float phi0 = (float)(Phi0 - floor(Phi0));
    const float phi1 = (float)(Phi1 - floor(Phi1));

    // per-lane interpolation weights and v envelopes
    const float w = (lowhalf ? ((float)k + 32.5f) : ((float)k - 31.5f)) * (1.0f / 64.0f);
    const float w1 = 1.0f - w;
    const float v00 = lowhalf ? vA : vB;   // frame0 sources
    const float v01 = lowhalf ? vB : vC;
    const float v10 = lowhalf ? vB : vC;   // frame1 sources
    const float v11 = lowhalf ? vC : vD;
    const float vu0 = 0.04f * (w1 * v00 + w * v01);
    const float vu1 = 0.04f * (w1 * v10 + w * v11);

    const int half = lowhalf ? 0 : 1;

    // ---- harmonic loops (frame0 then frame1), 4x unrolled ----
    #pragma unroll
    for (int f = 0; f < 2; ++f) {
        const int hmax = f ? hm1 : hm0;
        const float phi = f ? phi1 : phi0;
        const float W0 = (f ? vu1 : vu0) * w1;
        const float W1 = (f ? vu1 : vu0) * w;
        const float4* qb = &quads[f][p][half][0];

        float acc0 = 0.0f, acc1 = 0.0f, acc2 = 0.0f, acc3 = 0.0f;
        float nf0 = 1.0f, nf1 = 2.0f, nf2 = 3.0f, nf3 = 4.0f;

        for (int n0 = 1; n0 <= hmax; n0 += 4) {
            const float4 qa = qb[n0 - 1];
            const float4 qc = qb[n0 + 0];
            const float4 qd = qb[n0 + 1];
            const float4 qe = qb[n0 + 2];
            {
                const float cup = fmaf(W1, qa.y, W0 * qa.x);
                const float ph  = fmaf(nf0, phi, qa.z);
                acc0 = fmaf(cup, __builtin_amdgcn_sinf(__builtin_amdgcn_fractf(ph)), acc0);
            }
            {
                const float cup = fmaf(W1, qc.y, W0 * qc.x);
                const float ph  = fmaf(nf1, phi, qc.z);
                acc1 = fmaf(cup, __builtin_amdgcn_sinf(__builtin_amdgcn_fractf(ph)), acc1);
            }
            {
                const float cup = fmaf(W1, qd.y, W0 * qd.x);
                const float ph  = fmaf(nf2, phi, qd.z);
                acc2 = fmaf(cup, __builtin_amdgcn_sinf(__builtin_amdgcn_fractf(ph)), acc2);
            }
            {
                const float cup = fmaf(W1, qe.y, W0 * qe.x);
                const float ph  = fmaf(nf3, phi, qe.z);
                acc3 = fmaf(cup, __builtin_amdgcn_sinf(__builtin_amdgcn_fractf(ph)), acc3);
            }
            nf0 += 4.0f; nf1 += 4.0f; nf2 += 4.0f; nf3 += 4.0f;
        }
        part[f][p][k] = (acc0 + acc1) + (acc2 + acc3);
    }

    __syncthreads();
    if (tid < 128) {
        const int f = tid >> 6;
        const int j = tid & 63;
        float sum = 0.0f;
        #pragma unroll
        for (int q = 0; q < POLY; ++q) sum += part[f][q][j];
        out[(size_t)b * AUDIO + (t0 + f) * UP + j] = sum;
    }
}

extern "C" void kernel_launch(void* const* d_in, const int* in_sizes, int n_in,
                              void* d_out, int out_size, void* d_ws, size_t ws_size,
                              hipStream_t stream) {
    const float* f0 = (const float*)d_in[0];   // (2,8,500)
    const float* c  = (const float*)d_in[1];   // (2,8,64,500)
    const float* v  = (const float*)d_in[2];   // (2,8,500)
    // d_in[3] = a (loudness) — unused by the output
    const float* rp = (const float*)d_in[4];   // (2,512,1)
    float* out = (float*)d_out;                // (2,32000)

    k_fused<<<2 * (FRAMES / 2), 512, 0, stream>>>(f0, c, v, rp, out);
}